// Round 7
// baseline (348.447 us; speedup 1.0000x reference)
//
#include <hip/hip_runtime.h>

// Problem constants
#define B_   2
#define N_   2048
#define C_   1024
#define H_   16
#define D_   64
#define BH_  (B_*H_)      // 32
#define NDH  (N_*D_)      // 131072 elems per (b,h) plane
#define M1   (B_*N_)      // 4096 rows

typedef __attribute__((ext_vector_type(4))) float    f32x4;
typedef __attribute__((ext_vector_type(8))) _Float16 f16x8;
typedef __attribute__((ext_vector_type(4))) _Float16 f16x4;
typedef __attribute__((ext_vector_type(2))) __fp16   fp16v2;   // cvt_pkrtz return type

#define GLOAD_LDS(gp, lp) \
  __builtin_amdgcn_global_load_lds((const __attribute__((address_space(1))) void*)(gp), \
                                   (__attribute__((address_space(3))) void*)(lp), 16, 0, 0)

// ---------------- fp32 -> fp16 convert ----------------
__global__ void k_cvt16(const float* __restrict__ in, _Float16* __restrict__ out, int n4) {
  int i = blockIdx.x * blockDim.x + threadIdx.x;
  if (i >= n4) return;
  float4 v = ((const float4*)in)[i];
  f16x4 o;
  o.x = (_Float16)v.x; o.y = (_Float16)v.y; o.z = (_Float16)v.z; o.w = (_Float16)v.w;
  ((f16x4*)out)[i] = o;
}

// --- merged fp32->fp16 transpose for w_qkv and w_proj (+ amax zero-init) ---
__global__ __launch_bounds__(256) void k_transmerge(const float* __restrict__ wq,
                                                    const float* __restrict__ wp,
                                                    _Float16* __restrict__ whT,
                                                    _Float16* __restrict__ wpT,
                                                    unsigned* __restrict__ amax_u) {
  if (blockIdx.x == 0 && threadIdx.x < 64) amax_u[threadIdx.x] = 0u;
  __shared__ _Float16 t[64][68];
  int idx = blockIdx.x;
  const float* in; _Float16* out; int Cc, cx, cy;
  if (idx < 768) { in = wq; out = whT; Cc = 3072; cx = idx % 48; cy = idx / 48; }
  else { idx -= 768; in = wp; out = wpT; Cc = 1024; cx = idx % 16; cy = idx / 16; }
  const int R = 1024;
  int c0 = cx * 64, r0 = cy * 64;
  int tid = threadIdx.x;
  int cq = tid & 15, rq = tid >> 4;
#pragma unroll
  for (int i = 0; i < 4; ++i) {
    int r = rq + i * 16;
    float4 v = *(const float4*)(in + (size_t)(r0 + r) * Cc + c0 + cq * 4);
    t[r][cq*4+0] = (_Float16)v.x;
    t[r][cq*4+1] = (_Float16)v.y;
    t[r][cq*4+2] = (_Float16)v.z;
    t[r][cq*4+3] = (_Float16)v.w;
  }
  __syncthreads();
#pragma unroll
  for (int i = 0; i < 4; ++i) {
    int c = rq + i * 16;
    f16x4 o;
    o.x = t[cq*4+0][c];
    o.y = t[cq*4+1][c];
    o.z = t[cq*4+2][c];
    o.w = t[cq*4+3][c];
    *(f16x4*)(out + (size_t)(c0 + c) * R + r0 + cq * 4) = o;
  }
}

// ---------------- GEMM1: qkv = x @ w_qkv, async LDS staging --------------
__global__ __launch_bounds__(256) void k_gemm_qkv(const _Float16* __restrict__ A,
                                                  const _Float16* __restrict__ BT,
                                                  _Float16* __restrict__ qh,
                                                  _Float16* __restrict__ kh,
                                                  _Float16* __restrict__ vh,
                                                  unsigned* __restrict__ amax_u) {
  __shared__ __align__(16) _Float16 As[128 * 32];
  __shared__ __align__(16) _Float16 Bs[128 * 32];
  const int tid = threadIdx.x, lane = tid & 63, wave = tid >> 6;
  const int wm = wave >> 1, wn = wave & 1;
  const int mcol = lane & 15, quad = lane >> 4;
  const int m0 = blockIdx.x * 128, n0 = blockIdx.y * 128;
  f32x4 acc[4][4] = {};
  for (int k0 = 0; k0 < 1024; k0 += 32) {
#pragma unroll
    for (int r = 0; r < 2; ++r) {
      int c = tid + r * 256;
      int row = c >> 2, kc = c & 3;
      GLOAD_LDS(A  + (size_t)(m0 + row) * 1024 + k0 + kc * 8, &As[c * 8]);
      GLOAD_LDS(BT + (size_t)(n0 + row) * 1024 + k0 + kc * 8, &Bs[c * 8]);
    }
    __syncthreads();
    f16x8 af[4], bf[4];
#pragma unroll
    for (int tm = 0; tm < 4; ++tm)
      af[tm] = *(const f16x8*)&As[(wm * 64 + tm * 16 + mcol) * 32 + quad * 8];
#pragma unroll
    for (int tn = 0; tn < 4; ++tn)
      bf[tn] = *(const f16x8*)&Bs[(wn * 64 + tn * 16 + mcol) * 32 + quad * 8];
#pragma unroll
    for (int tm = 0; tm < 4; ++tm)
#pragma unroll
      for (int tn = 0; tn < 4; ++tn)
        acc[tm][tn] = __builtin_amdgcn_mfma_f32_16x16x32_f16(af[tm], bf[tn], acc[tm][tn], 0, 0, 0);
    __syncthreads();
  }
  const int sec = n0 >> 10;
  if (sec < 2) {
    _Float16* dst = sec ? kh : qh;
    float mxv = 0.f;
#pragma unroll
    for (int tm = 0; tm < 4; ++tm)
#pragma unroll
      for (int tn = 0; tn < 4; ++tn) {
        int rowb = m0 + wm * 64 + tm * 16 + quad * 4;
        int col = n0 + wn * 64 + tn * 16 + mcol;
        int cc = col & 1023, h = cc >> 6, d = cc & 63;
        int b = rowb >> 11, n = rowb & 2047;
        f32x4 a = acc[tm][tn];
        mxv = fmaxf(mxv, fmaxf(fmaxf(fabsf(a[0]), fabsf(a[1])),
                               fmaxf(fabsf(a[2]), fabsf(a[3]))));
        f16x4 o;
        o.x = (_Float16)a[0]; o.y = (_Float16)a[1];
        o.z = (_Float16)a[2]; o.w = (_Float16)a[3];
        *(f16x4*)&dst[(size_t)(b * 16 + h) * 131072 + (size_t)(n >> 5) * 2048 + d * 32 + (n & 31)] = o;
      }
#pragma unroll
    for (int off = 32; off; off >>= 1) mxv = fmaxf(mxv, __shfl_xor(mxv, off));
    if (lane == 0) {
      int head = ((n0 & 1023) >> 6) + wn;
      int plane = (m0 >> 11) * 16 + head;
      atomicMax(&amax_u[sec * 32 + plane], __float_as_uint(mxv));
    }
  } else {
#pragma unroll
    for (int tm = 0; tm < 4; ++tm)
#pragma unroll
      for (int tn = 0; tn < 4; ++tn) {
        int rowb = m0 + wm * 64 + tm * 16 + quad * 4;
        int col = n0 + wn * 64 + tn * 16 + mcol;
        int cc = col & 1023, h = cc >> 6, d = cc & 63;
        int b = rowb >> 11, n = rowb & 2047;
        f16x4 o;
        o.x = (_Float16)acc[tm][tn][0];
        o.y = (_Float16)acc[tm][tn][1];
        o.z = (_Float16)acc[tm][tn][2];
        o.w = (_Float16)acc[tm][tn][3];
        *(f16x4*)&vh[(size_t)(b * 16 + h) * 131072 + (size_t)(n >> 5) * 2048 + d * 32 + (n & 31)] = o;
      }
  }
}

// ---------------- fp8 e4m3 quantize (tiled fp16 in, LDS transpose) -------
__global__ __launch_bounds__(256) void k_quant(const _Float16* __restrict__ qh,
                                               const _Float16* __restrict__ kh,
                                               const float* __restrict__ amax,
                                               char* __restrict__ q8,
                                               char* __restrict__ k8) {
  __shared__ ushort T[32][72];
  int blk = blockIdx.x;
  int which = blk >> 11;
  int idx = blk & 2047;
  int bh = idx >> 6, chunk = idx & 63;
  const _Float16* src = (which ? kh : qh) + (size_t)bh * NDH + chunk * 2048;
  float s = 448.f / fmaxf(amax[which * 32 + bh], 1e-12f);
  int t = threadIdx.x;
  f16x8 v = *(const f16x8*)(src + t * 8);
  int d = t >> 2, kk0 = (t & 3) * 8;
#pragma unroll
  for (int j = 0; j < 8; ++j) T[kk0 + j][d] = ((const ushort*)&v)[j];
  __syncthreads();
  int r = t >> 3, d0 = (t & 7) * 8;
  f16x8 row = *(const f16x8*)&T[r][d0];
  float f[8];
#pragma unroll
  for (int j = 0; j < 8; ++j) f[j] = (float)((const _Float16*)&row)[j] * s;
  int lo = 0, hi = 0;
  lo = __builtin_amdgcn_cvt_pk_fp8_f32(f[0], f[1], lo, false);
  lo = __builtin_amdgcn_cvt_pk_fp8_f32(f[2], f[3], lo, true);
  hi = __builtin_amdgcn_cvt_pk_fp8_f32(f[4], f[5], hi, false);
  hi = __builtin_amdgcn_cvt_pk_fp8_f32(f[6], f[7], hi, true);
  int2 o; o.x = lo; o.y = hi;
  if (which == 0) {
    char* dst = q8 + (size_t)bh * NDH + (size_t)(chunk * 32 + r) * 64 + d0;
    *(int2*)dst = o;
  } else {
    int e = (r >> 2) & 1;
    int mc = (r >> 3) * 4 + (r & 3);
    int kb = d0 >> 5, dq = (d0 >> 3) & 3;
    char* dst = k8 + (size_t)bh * NDH + chunk * 2048 + (e * 2 + kb) * 512 + mc * 32 + dq * 8;
    *(int2*)dst = o;
  }
}

// ---------------- flash causal attention, K-split 2x ---------------------
// Block = 4 waves = 2 pairs x {lead, tail}. Pair {ga=pr, gb=127-pr}:
//   lead: group-a tiles (ta<=8, emits A) + first 9-ta b-tiles  (9 tiles)
//   tail: last 8 b-tiles (diagonal masked)                     (8 tiles)
// Tail ships (m,l,O) via LDS; lead merges and stores group b.
__global__ __launch_bounds__(256, 4) void k_flash(const char* __restrict__ q8,
                                                  const char* __restrict__ k8,
                                                  const _Float16* __restrict__ vh,
                                                  const float* __restrict__ amax,
                                                  _Float16* __restrict__ attn) {
  __shared__ float Osh[2][16][68];   // +4 pad: 2-way (free) b128 pattern
  __shared__ float Msh[2][16], Lsh[2][16];
  const int bh = blockIdx.x;
  const int wave = threadIdx.x >> 6, lane = threadIdx.x & 63;
  const int mcol = lane & 15, quad = lane >> 4;
  const int pi = wave >> 1, role = wave & 1;      // role 0=lead, 1=tail
  const int pr = blockIdx.y * 2 + pi;             // pair 0..63
  const int ga = pr, gb = 127 - pr;
  const int ta = (ga >> 3) + 1;                   // 1..8

  float sq = 448.f / fmaxf(amax[bh], 1e-12f);
  float sk = 448.f / fmaxf(amax[32 + bh], 1e-12f);
  const float c2 = (1.f / (sq * sk)) * 0.125f * 1.44269504089f;

  const size_t pbase = (size_t)bh * NDH;
  const char* kbase = k8 + pbase + mcol * 32 + quad * 8;
  const _Float16* vbase = vh + pbase + mcol * 32 + quad * 8;
  const int qrowA = ga * 16 + mcol, qrowB = gb * 16 + mcol;

  long aq0v, aq1v;   // current segment's Q frag (lead: A then B; tail: B)
  { int qr = role ? qrowB : qrowA;
    const char* qp = q8 + pbase + (size_t)qr * 64;
    aq0v = *(const long*)(qp + quad * 8); aq1v = *(const long*)(qp + 32 + quad * 8); }

  f32x4 O[4] = {};
  float m_i = -3e38f, l_i = 0.f;
  const int b = bh >> 4, h = bh & 15;
  const int kq = quad * 8;
  const int NT = role ? 8 : 9;

  auto u_n0 = [&](int u) -> int {
    if (role) return (9 - ta + u) << 7;
    return (u < ta ? u : u - ta) << 7;
  };

  long kc[16], kn[16];
  {
    const char* kp = kbase + (size_t)(u_n0(0) >> 5) * 2048;
#pragma unroll
    for (int i = 0; i < 16; ++i) kc[i] = *(const long*)(kp + i * 512);
  }

  auto body = [&](int u, long (&cur)[16], long (&nxt)[16]) {
    const bool inA = (!role) && (u < ta);
    const int n0 = u_n0(u);
    const int qrow = inA ? qrowA : qrowB;
    const bool maskT = role ? (u == 7) : (u == ta - 1);
    const bool emitA = (!role) && (u == ta - 1);

    f32x4 s[4][2];
#pragma unroll
    for (int p = 0; p < 4; ++p)
#pragma unroll
      for (int e = 0; e < 2; ++e) {
        f32x4 z = {};
        z = __builtin_amdgcn_mfma_f32_16x16x32_fp8_fp8(cur[p * 4 + e * 2 + 0], aq0v, z, 0, 0, 0);
        z = __builtin_amdgcn_mfma_f32_16x16x32_fp8_fp8(cur[p * 4 + e * 2 + 1], aq1v, z, 0, 0, 0);
        s[p][e] = z;
      }
    f16x8 va[4][4];
    {
      const _Float16* vp = vbase + (size_t)(n0 >> 5) * 2048;
#pragma unroll
      for (int p = 0; p < 4; ++p)
#pragma unroll
        for (int dt = 0; dt < 4; ++dt)
          va[dt][p] = *(const f16x8*)(vp + p * 2048 + dt * 512);
    }
    if (u + 1 < NT) {
      const char* kp = kbase + (size_t)(u_n0(u + 1) >> 5) * 2048;
#pragma unroll
      for (int i = 0; i < 16; ++i) nxt[i] = *(const long*)(kp + i * 512);
    }
    // raw-domain mask, then fold c2 into the exp2 via fma
    if (maskT) {
#pragma unroll
      for (int p = 0; p < 4; ++p)
#pragma unroll
        for (int e = 0; e < 2; ++e)
#pragma unroll
          for (int r = 0; r < 4; ++r) {
            int key = n0 + p * 32 + kq + e * 4 + r;
            s[p][e][r] = (key <= qrow) ? s[p][e][r] : -3e38f;
          }
    }
    float fm[8];
#pragma unroll
    for (int p = 0; p < 4; ++p)
#pragma unroll
      for (int e = 0; e < 2; ++e) {
        f32x4 v = s[p][e];
        fm[p * 2 + e] = fmaxf(fmaxf(v[0], v[1]), fmaxf(v[2], v[3]));
      }
    float rm = fmaxf(fmaxf(fmaxf(fm[0], fm[1]), fmaxf(fm[2], fm[3])),
                     fmaxf(fmaxf(fm[4], fm[5]), fmaxf(fm[6], fm[7])));
    float mx = fmaxf(m_i, rm * c2);
    mx = fmaxf(mx, __shfl_xor(mx, 16));
    mx = fmaxf(mx, __shfl_xor(mx, 32));
    float alpha = exp2f(m_i - mx);
    m_i = mx;
    float fs[8];
    union { f16x8 v8; fp16v2 v2[4]; } pb[4];
#pragma unroll
    for (int p = 0; p < 4; ++p)
#pragma unroll
      for (int e = 0; e < 2; ++e) {
        float p0 = exp2f(__builtin_fmaf(s[p][e][0], c2, -mx));
        float p1 = exp2f(__builtin_fmaf(s[p][e][1], c2, -mx));
        float p2 = exp2f(__builtin_fmaf(s[p][e][2], c2, -mx));
        float p3 = exp2f(__builtin_fmaf(s[p][e][3], c2, -mx));
        pb[p].v2[e * 2 + 0] = __builtin_amdgcn_cvt_pkrtz(p0, p1);
        pb[p].v2[e * 2 + 1] = __builtin_amdgcn_cvt_pkrtz(p2, p3);
        fs[p * 2 + e] = (p0 + p1) + (p2 + p3);
      }
    float sum = ((fs[0] + fs[1]) + (fs[2] + fs[3])) + ((fs[4] + fs[5]) + (fs[6] + fs[7]));
    sum += __shfl_xor(sum, 16);
    sum += __shfl_xor(sum, 32);
    l_i = l_i * alpha + sum;
#pragma unroll
    for (int dt = 0; dt < 4; ++dt)
#pragma unroll
      for (int r = 0; r < 4; ++r)
        O[dt][r] *= alpha;
#pragma unroll
    for (int p = 0; p < 4; ++p)
#pragma unroll
      for (int dt = 0; dt < 4; ++dt)
        O[dt] = __builtin_amdgcn_mfma_f32_16x16x32_f16(va[dt][p], pb[p].v8, O[dt], 0, 0, 0);
    if (emitA) {
      float rl = 1.f / l_i;
      _Float16* op = attn + ((size_t)b * 2048 + qrowA) * 1024 + h * 64;
#pragma unroll
      for (int dt = 0; dt < 4; ++dt) {
        f16x4 o;
        o.x = (_Float16)(O[dt][0] * rl);
        o.y = (_Float16)(O[dt][1] * rl);
        o.z = (_Float16)(O[dt][2] * rl);
        o.w = (_Float16)(O[dt][3] * rl);
        *(f16x4*)(op + dt * 16 + quad * 4) = o;
        O[dt] = (f32x4){0.f, 0.f, 0.f, 0.f};
      }
      m_i = -3e38f; l_i = 0.f;
      // switch Q fragment to group b
      const char* qp = q8 + pbase + (size_t)qrowB * 64;
      aq0v = *(const long*)(qp + quad * 8);
      aq1v = *(const long*)(qp + 32 + quad * 8);
    }
  };

#pragma unroll 1
  for (int u = 0; u < NT; u += 2) {
    body(u, kc, kn);
    if (u + 1 < NT) body(u + 1, kn, kc);
  }

  if (role) {   // tail ships partial state
#pragma unroll
    for (int dt = 0; dt < 4; ++dt)
      *(f32x4*)&Osh[pi][mcol][dt * 16 + quad * 4] = O[dt];
    if (quad == 0) { Msh[pi][mcol] = m_i; Lsh[pi][mcol] = l_i; }
  }
  __syncthreads();
  if (!role) {  // lead merges and stores group b
    float m1 = Msh[pi][mcol], l1 = Lsh[pi][mcol];
    float m = fmaxf(m_i, m1);
    float a0 = exp2f(m_i - m), a1 = exp2f(m1 - m);
    float rl = 1.f / (a0 * l_i + a1 * l1);
    _Float16* op = attn + ((size_t)b * 2048 + qrowB) * 1024 + h * 64;
#pragma unroll
    for (int dt = 0; dt < 4; ++dt) {
      f32x4 o1 = *(const f32x4*)&Osh[pi][mcol][dt * 16 + quad * 4];
      f16x4 o;
      o.x = (_Float16)((a0 * O[dt][0] + a1 * o1[0]) * rl);
      o.y = (_Float16)((a0 * O[dt][1] + a1 * o1[1]) * rl);
      o.z = (_Float16)((a0 * O[dt][2] + a1 * o1[2]) * rl);
      o.w = (_Float16)((a0 * O[dt][3] + a1 * o1[3]) * rl);
      *(f16x4*)(op + dt * 16 + quad * 4) = o;
    }
  }
}

// ---------------- GEMM2: out = attn @ w_proj + b (async staging) ---------
__global__ __launch_bounds__(256) void k_gemm_out(const _Float16* __restrict__ A,
                                                  const _Float16* __restrict__ BT,
                                                  const float* __restrict__ bias,
                                                  float* __restrict__ out) {
  __shared__ __align__(16) _Float16 As[128 * 32];
  __shared__ __align__(16) _Float16 Bs[128 * 32];
  const int tid = threadIdx.x, lane = tid & 63, wave = tid >> 6;
  const int wm = wave >> 1, wn = wave & 1;
  const int mcol = lane & 15, quad = lane >> 4;
  const int m0 = blockIdx.x * 128, n0 = blockIdx.y * 128;
  f32x4 acc[4][4] = {};
  for (int k0 = 0; k0 < 1024; k0 += 32) {
#pragma unroll
    for (int r = 0; r < 2; ++r) {
      int c = tid + r * 256;
      int row = c >> 2, kc = c & 3;
      GLOAD_LDS(A  + (size_t)(m0 + row) * 1024 + k0 + kc * 8, &As[c * 8]);
      GLOAD_LDS(BT + (size_t)(n0 + row) * 1024 + k0 + kc * 8, &Bs[c * 8]);
    }
    __syncthreads();
    f16x8 af[4], bf[4];
#pragma unroll
    for (int tm = 0; tm < 4; ++tm)
      af[tm] = *(const f16x8*)&As[(wm * 64 + tm * 16 + mcol) * 32 + quad * 8];
#pragma unroll
    for (int tn = 0; tn < 4; ++tn)
      bf[tn] = *(const f16x8*)&Bs[(wn * 64 + tn * 16 + mcol) * 32 + quad * 8];
#pragma unroll
    for (int tm = 0; tm < 4; ++tm)
#pragma unroll
      for (int tn = 0; tn < 4; ++tn)
        acc[tm][tn] = __builtin_amdgcn_mfma_f32_16x16x32_f16(af[tm], bf[tn], acc[tm][tn], 0, 0, 0);
    __syncthreads();
  }
#pragma unroll
  for (int tm = 0; tm < 4; ++tm)
#pragma unroll
    for (int tn = 0; tn < 4; ++tn)
#pragma unroll
      for (int reg = 0; reg < 4; ++reg) {
        int row = m0 + wm * 64 + tm * 16 + quad * 4 + reg;
        int col = n0 + wn * 64 + tn * 16 + mcol;
        out[(size_t)row * 1024 + col] = acc[tm][tn][reg] + bias[col];
      }
}

extern "C" void kernel_launch(void* const* d_in, const int* in_sizes, int n_in,
                              void* d_out, int out_size, void* d_ws, size_t ws_size,
                              hipStream_t stream) {
  const float* x      = (const float*)d_in[0];
  const float* w_qkv  = (const float*)d_in[1];
  const float* w_proj = (const float*)d_in[2];
  const float* b_proj = (const float*)d_in[3];
  float* out = (float*)d_out;

  char* ws = (char*)d_ws;
  _Float16* xh   = (_Float16*)ws; ws += (size_t)M1 * C_ * 2;
  _Float16* whT  = (_Float16*)ws; ws += (size_t)3 * C_ * C_ * 2;
  _Float16* wpT  = (_Float16*)ws; ws += (size_t)C_ * C_ * 2;
  _Float16* qh   = (_Float16*)ws; ws += (size_t)BH_ * NDH * 2;
  _Float16* kh   = (_Float16*)ws; ws += (size_t)BH_ * NDH * 2;
  _Float16* vh   = (_Float16*)ws; ws += (size_t)BH_ * NDH * 2;
  char*     q8   = (char*)ws;     ws += (size_t)BH_ * NDH;
  char*     k8   = (char*)ws;     ws += (size_t)BH_ * NDH;
  _Float16* attn = (_Float16*)ws; ws += (size_t)M1 * C_ * 2;
  float*    amx  = (float*)ws;    ws += 256;

  k_cvt16<<<(M1 * C_ / 4 + 255) / 256, 256, 0, stream>>>(x, xh, M1 * C_ / 4);
  k_transmerge<<<1024, 256, 0, stream>>>(w_qkv, w_proj, whT, wpT, (unsigned*)amx);
  k_gemm_qkv<<<dim3(M1 / 128, 3 * C_ / 128), 256, 0, stream>>>(xh, whT, qh, kh, vh, (unsigned*)amx);
  k_quant<<<4096, 256, 0, stream>>>(qh, kh, amx, q8, k8);
  k_flash<<<dim3(32, 32), 256, 0, stream>>>(q8, k8, vh, amx, attn);
  k_gemm_out<<<dim3(M1 / 128, C_ / 128), 256, 0, stream>>>(attn, wpT, b_proj, out);
}

// Round 8
// 215.744 us; speedup vs baseline: 1.6151x; 1.6151x over previous
//
#include <hip/hip_runtime.h>

// Problem constants
#define B_   2
#define N_   2048
#define C_   1024
#define H_   16
#define D_   64
#define BH_  (B_*H_)      // 32
#define NDH  (N_*D_)      // 131072 elems per (b,h) plane
#define M1   (B_*N_)      // 4096 rows

typedef __attribute__((ext_vector_type(4))) float    f32x4;
typedef __attribute__((ext_vector_type(8))) _Float16 f16x8;
typedef __attribute__((ext_vector_type(4))) _Float16 f16x4;
typedef __attribute__((ext_vector_type(2))) __fp16   fp16v2;   // cvt_pkrtz return type

#define GLOAD_LDS(gp, lp) \
  __builtin_amdgcn_global_load_lds((const __attribute__((address_space(1))) void*)(gp), \
                                   (__attribute__((address_space(3))) void*)(lp), 16, 0, 0)

// ---------------- fp32 -> fp16 convert ----------------
__global__ void k_cvt16(const float* __restrict__ in, _Float16* __restrict__ out, int n4) {
  int i = blockIdx.x * blockDim.x + threadIdx.x;
  if (i >= n4) return;
  float4 v = ((const float4*)in)[i];
  f16x4 o;
  o.x = (_Float16)v.x; o.y = (_Float16)v.y; o.z = (_Float16)v.z; o.w = (_Float16)v.w;
  ((f16x4*)out)[i] = o;
}

// --- merged fp32->fp16 transpose for w_qkv and w_proj (+ amax zero-init) ---
__global__ __launch_bounds__(256) void k_transmerge(const float* __restrict__ wq,
                                                    const float* __restrict__ wp,
                                                    _Float16* __restrict__ whT,
                                                    _Float16* __restrict__ wpT,
                                                    unsigned* __restrict__ amax_u) {
  if (blockIdx.x == 0 && threadIdx.x < 64) amax_u[threadIdx.x] = 0u;
  __shared__ _Float16 t[64][68];
  int idx = blockIdx.x;
  const float* in; _Float16* out; int Cc, cx, cy;
  if (idx < 768) { in = wq; out = whT; Cc = 3072; cx = idx % 48; cy = idx / 48; }
  else { idx -= 768; in = wp; out = wpT; Cc = 1024; cx = idx % 16; cy = idx / 16; }
  const int R = 1024;
  int c0 = cx * 64, r0 = cy * 64;
  int tid = threadIdx.x;
  int cq = tid & 15, rq = tid >> 4;
#pragma unroll
  for (int i = 0; i < 4; ++i) {
    int r = rq + i * 16;
    float4 v = *(const float4*)(in + (size_t)(r0 + r) * Cc + c0 + cq * 4);
    t[r][cq*4+0] = (_Float16)v.x;
    t[r][cq*4+1] = (_Float16)v.y;
    t[r][cq*4+2] = (_Float16)v.z;
    t[r][cq*4+3] = (_Float16)v.w;
  }
  __syncthreads();
#pragma unroll
  for (int i = 0; i < 4; ++i) {
    int c = rq + i * 16;
    f16x4 o;
    o.x = t[cq*4+0][c];
    o.y = t[cq*4+1][c];
    o.z = t[cq*4+2][c];
    o.w = t[cq*4+3][c];
    *(f16x4*)(out + (size_t)(c0 + c) * R + r0 + cq * 4) = o;
  }
}

// ---------------- GEMM1: qkv = x @ w_qkv, async LDS staging --------------
__global__ __launch_bounds__(256) void k_gemm_qkv(const _Float16* __restrict__ A,
                                                  const _Float16* __restrict__ BT,
                                                  _Float16* __restrict__ qh,
                                                  _Float16* __restrict__ kh,
                                                  _Float16* __restrict__ vh,
                                                  unsigned* __restrict__ amax_u) {
  __shared__ __align__(16) _Float16 As[128 * 32];
  __shared__ __align__(16) _Float16 Bs[128 * 32];
  const int tid = threadIdx.x, lane = tid & 63, wave = tid >> 6;
  const int wm = wave >> 1, wn = wave & 1;
  const int mcol = lane & 15, quad = lane >> 4;
  const int m0 = blockIdx.x * 128, n0 = blockIdx.y * 128;
  f32x4 acc[4][4] = {};
  for (int k0 = 0; k0 < 1024; k0 += 32) {
#pragma unroll
    for (int r = 0; r < 2; ++r) {
      int c = tid + r * 256;
      int row = c >> 2, kc = c & 3;
      GLOAD_LDS(A  + (size_t)(m0 + row) * 1024 + k0 + kc * 8, &As[c * 8]);
      GLOAD_LDS(BT + (size_t)(n0 + row) * 1024 + k0 + kc * 8, &Bs[c * 8]);
    }
    __syncthreads();
    f16x8 af[4], bf[4];
#pragma unroll
    for (int tm = 0; tm < 4; ++tm)
      af[tm] = *(const f16x8*)&As[(wm * 64 + tm * 16 + mcol) * 32 + quad * 8];
#pragma unroll
    for (int tn = 0; tn < 4; ++tn)
      bf[tn] = *(const f16x8*)&Bs[(wn * 64 + tn * 16 + mcol) * 32 + quad * 8];
#pragma unroll
    for (int tm = 0; tm < 4; ++tm)
#pragma unroll
      for (int tn = 0; tn < 4; ++tn)
        acc[tm][tn] = __builtin_amdgcn_mfma_f32_16x16x32_f16(af[tm], bf[tn], acc[tm][tn], 0, 0, 0);
    __syncthreads();
  }
  const int sec = n0 >> 10;
  if (sec < 2) {
    _Float16* dst = sec ? kh : qh;
    float mxv = 0.f;
#pragma unroll
    for (int tm = 0; tm < 4; ++tm)
#pragma unroll
      for (int tn = 0; tn < 4; ++tn) {
        int rowb = m0 + wm * 64 + tm * 16 + quad * 4;
        int col = n0 + wn * 64 + tn * 16 + mcol;
        int cc = col & 1023, h = cc >> 6, d = cc & 63;
        int b = rowb >> 11, n = rowb & 2047;
        f32x4 a = acc[tm][tn];
        mxv = fmaxf(mxv, fmaxf(fmaxf(fabsf(a[0]), fabsf(a[1])),
                               fmaxf(fabsf(a[2]), fabsf(a[3]))));
        f16x4 o;
        o.x = (_Float16)a[0]; o.y = (_Float16)a[1];
        o.z = (_Float16)a[2]; o.w = (_Float16)a[3];
        *(f16x4*)&dst[(size_t)(b * 16 + h) * 131072 + (size_t)(n >> 5) * 2048 + d * 32 + (n & 31)] = o;
      }
#pragma unroll
    for (int off = 32; off; off >>= 1) mxv = fmaxf(mxv, __shfl_xor(mxv, off));
    if (lane == 0) {
      int head = ((n0 & 1023) >> 6) + wn;
      int plane = (m0 >> 11) * 16 + head;
      atomicMax(&amax_u[sec * 32 + plane], __float_as_uint(mxv));
    }
  } else {
#pragma unroll
    for (int tm = 0; tm < 4; ++tm)
#pragma unroll
      for (int tn = 0; tn < 4; ++tn) {
        int rowb = m0 + wm * 64 + tm * 16 + quad * 4;
        int col = n0 + wn * 64 + tn * 16 + mcol;
        int cc = col & 1023, h = cc >> 6, d = cc & 63;
        int b = rowb >> 11, n = rowb & 2047;
        f16x4 o;
        o.x = (_Float16)acc[tm][tn][0];
        o.y = (_Float16)acc[tm][tn][1];
        o.z = (_Float16)acc[tm][tn][2];
        o.w = (_Float16)acc[tm][tn][3];
        *(f16x4*)&vh[(size_t)(b * 16 + h) * 131072 + (size_t)(n >> 5) * 2048 + d * 32 + (n & 31)] = o;
      }
  }
}

// ---------------- fp8 e4m3 quantize (tiled fp16 in, LDS transpose) -------
__global__ __launch_bounds__(256) void k_quant(const _Float16* __restrict__ qh,
                                               const _Float16* __restrict__ kh,
                                               const float* __restrict__ amax,
                                               char* __restrict__ q8,
                                               char* __restrict__ k8) {
  __shared__ ushort T[32][72];
  int blk = blockIdx.x;
  int which = blk >> 11;
  int idx = blk & 2047;
  int bh = idx >> 6, chunk = idx & 63;
  const _Float16* src = (which ? kh : qh) + (size_t)bh * NDH + chunk * 2048;
  float s = 448.f / fmaxf(amax[which * 32 + bh], 1e-12f);
  int t = threadIdx.x;
  f16x8 v = *(const f16x8*)(src + t * 8);
  int d = t >> 2, kk0 = (t & 3) * 8;
#pragma unroll
  for (int j = 0; j < 8; ++j) T[kk0 + j][d] = ((const ushort*)&v)[j];
  __syncthreads();
  int r = t >> 3, d0 = (t & 7) * 8;
  f16x8 row = *(const f16x8*)&T[r][d0];
  float f[8];
#pragma unroll
  for (int j = 0; j < 8; ++j) f[j] = (float)((const _Float16*)&row)[j] * s;
  int lo = 0, hi = 0;
  lo = __builtin_amdgcn_cvt_pk_fp8_f32(f[0], f[1], lo, false);
  lo = __builtin_amdgcn_cvt_pk_fp8_f32(f[2], f[3], lo, true);
  hi = __builtin_amdgcn_cvt_pk_fp8_f32(f[4], f[5], hi, false);
  hi = __builtin_amdgcn_cvt_pk_fp8_f32(f[6], f[7], hi, true);
  int2 o; o.x = lo; o.y = hi;
  if (which == 0) {
    char* dst = q8 + (size_t)bh * NDH + (size_t)(chunk * 32 + r) * 64 + d0;
    *(int2*)dst = o;
  } else {
    int e = (r >> 2) & 1;
    int mc = (r >> 3) * 4 + (r & 3);
    int kb = d0 >> 5, dq = (d0 >> 3) & 3;
    char* dst = k8 + (size_t)bh * NDH + chunk * 2048 + (e * 2 + kb) * 512 + mc * 32 + dq * 8;
    *(int2*)dst = o;
  }
}

// ---------------- flash causal attention, K-split 2x ---------------------
// Block = 4 waves = 2 pairs x {lead, tail}. Pair {ga=pr, gb=127-pr}:
//   lead: group-a tiles (ta<=8, emits A) + first 9-ta b-tiles  (9 tiles)
//   tail: last 8 b-tiles (diagonal masked)                     (8 tiles)
// Tail ships (m,l,O) via LDS; lead merges and stores group b.
// NOTE: launch_bounds(256,2) — requesting 4 waves/EU made the allocator cap
// VGPRs at 64 and spill ~450 MB to scratch (R7). At (256,2) the kernel fits
// in ~124 VGPRs < 128, so 4 waves/SIMD co-reside naturally.
__global__ __launch_bounds__(256, 2) void k_flash(const char* __restrict__ q8,
                                                  const char* __restrict__ k8,
                                                  const _Float16* __restrict__ vh,
                                                  const float* __restrict__ amax,
                                                  _Float16* __restrict__ attn) {
  __shared__ float Osh[2][16][68];   // +4 pad: 2-way (free) b128 pattern
  __shared__ float Msh[2][16], Lsh[2][16];
  const int bh = blockIdx.x;
  const int wave = threadIdx.x >> 6, lane = threadIdx.x & 63;
  const int mcol = lane & 15, quad = lane >> 4;
  const int pi = wave >> 1, role = wave & 1;      // role 0=lead, 1=tail
  const int pr = blockIdx.y * 2 + pi;             // pair 0..63
  const int ga = pr, gb = 127 - pr;
  const int ta = (ga >> 3) + 1;                   // 1..8

  float sq = 448.f / fmaxf(amax[bh], 1e-12f);
  float sk = 448.f / fmaxf(amax[32 + bh], 1e-12f);
  const float c2 = (1.f / (sq * sk)) * 0.125f * 1.44269504089f;

  const size_t pbase = (size_t)bh * NDH;
  const char* kbase = k8 + pbase + mcol * 32 + quad * 8;
  const _Float16* vbase = vh + pbase + mcol * 32 + quad * 8;
  const int qrowA = ga * 16 + mcol, qrowB = gb * 16 + mcol;

  long aq0v, aq1v;   // current segment's Q frag (lead: A then B; tail: B)
  { int qr = role ? qrowB : qrowA;
    const char* qp = q8 + pbase + (size_t)qr * 64;
    aq0v = *(const long*)(qp + quad * 8); aq1v = *(const long*)(qp + 32 + quad * 8); }

  f32x4 O[4] = {};
  float m_i = -3e38f, l_i = 0.f;
  const int b = bh >> 4, h = bh & 15;
  const int kq = quad * 8;
  const int NT = role ? 8 : 9;

  auto u_n0 = [&](int u) -> int {
    if (role) return (9 - ta + u) << 7;
    return (u < ta ? u : u - ta) << 7;
  };

  long kc[16], kn[16];
  {
    const char* kp = kbase + (size_t)(u_n0(0) >> 5) * 2048;
#pragma unroll
    for (int i = 0; i < 16; ++i) kc[i] = *(const long*)(kp + i * 512);
  }

  auto body = [&](int u, long (&cur)[16], long (&nxt)[16]) {
    const bool inA = (!role) && (u < ta);
    const int n0 = u_n0(u);
    const int qrow = inA ? qrowA : qrowB;
    const bool maskT = role ? (u == 7) : (u == ta - 1);
    const bool emitA = (!role) && (u == ta - 1);

    f32x4 s[4][2];
#pragma unroll
    for (int p = 0; p < 4; ++p)
#pragma unroll
      for (int e = 0; e < 2; ++e) {
        f32x4 z = {};
        z = __builtin_amdgcn_mfma_f32_16x16x32_fp8_fp8(cur[p * 4 + e * 2 + 0], aq0v, z, 0, 0, 0);
        z = __builtin_amdgcn_mfma_f32_16x16x32_fp8_fp8(cur[p * 4 + e * 2 + 1], aq1v, z, 0, 0, 0);
        s[p][e] = z;
      }
    f16x8 va[4][4];
    {
      const _Float16* vp = vbase + (size_t)(n0 >> 5) * 2048;
#pragma unroll
      for (int p = 0; p < 4; ++p)
#pragma unroll
        for (int dt = 0; dt < 4; ++dt)
          va[dt][p] = *(const f16x8*)(vp + p * 2048 + dt * 512);
    }
    if (u + 1 < NT) {
      const char* kp = kbase + (size_t)(u_n0(u + 1) >> 5) * 2048;
#pragma unroll
      for (int i = 0; i < 16; ++i) nxt[i] = *(const long*)(kp + i * 512);
    }
    // raw-domain mask, then fold c2 into the exp2 via fma
    if (maskT) {
#pragma unroll
      for (int p = 0; p < 4; ++p)
#pragma unroll
        for (int e = 0; e < 2; ++e)
#pragma unroll
          for (int r = 0; r < 4; ++r) {
            int key = n0 + p * 32 + kq + e * 4 + r;
            s[p][e][r] = (key <= qrow) ? s[p][e][r] : -3e38f;
          }
    }
    float fm[8];
#pragma unroll
    for (int p = 0; p < 4; ++p)
#pragma unroll
      for (int e = 0; e < 2; ++e) {
        f32x4 v = s[p][e];
        fm[p * 2 + e] = fmaxf(fmaxf(v[0], v[1]), fmaxf(v[2], v[3]));
      }
    float rm = fmaxf(fmaxf(fmaxf(fm[0], fm[1]), fmaxf(fm[2], fm[3])),
                     fmaxf(fmaxf(fm[4], fm[5]), fmaxf(fm[6], fm[7])));
    float mx = fmaxf(m_i, rm * c2);
    mx = fmaxf(mx, __shfl_xor(mx, 16));
    mx = fmaxf(mx, __shfl_xor(mx, 32));
    float alpha = exp2f(m_i - mx);
    m_i = mx;
    float fs[8];
    union { f16x8 v8; fp16v2 v2[4]; } pb[4];
#pragma unroll
    for (int p = 0; p < 4; ++p)
#pragma unroll
      for (int e = 0; e < 2; ++e) {
        float p0 = exp2f(__builtin_fmaf(s[p][e][0], c2, -mx));
        float p1 = exp2f(__builtin_fmaf(s[p][e][1], c2, -mx));
        float p2 = exp2f(__builtin_fmaf(s[p][e][2], c2, -mx));
        float p3 = exp2f(__builtin_fmaf(s[p][e][3], c2, -mx));
        pb[p].v2[e * 2 + 0] = __builtin_amdgcn_cvt_pkrtz(p0, p1);
        pb[p].v2[e * 2 + 1] = __builtin_amdgcn_cvt_pkrtz(p2, p3);
        fs[p * 2 + e] = (p0 + p1) + (p2 + p3);
      }
    float sum = ((fs[0] + fs[1]) + (fs[2] + fs[3])) + ((fs[4] + fs[5]) + (fs[6] + fs[7]));
    sum += __shfl_xor(sum, 16);
    sum += __shfl_xor(sum, 32);
    l_i = l_i * alpha + sum;
#pragma unroll
    for (int dt = 0; dt < 4; ++dt)
#pragma unroll
      for (int r = 0; r < 4; ++r)
        O[dt][r] *= alpha;
#pragma unroll
    for (int p = 0; p < 4; ++p)
#pragma unroll
      for (int dt = 0; dt < 4; ++dt)
        O[dt] = __builtin_amdgcn_mfma_f32_16x16x32_f16(va[dt][p], pb[p].v8, O[dt], 0, 0, 0);
    if (emitA) {
      float rl = 1.f / l_i;
      _Float16* op = attn + ((size_t)b * 2048 + qrowA) * 1024 + h * 64;
#pragma unroll
      for (int dt = 0; dt < 4; ++dt) {
        f16x4 o;
        o.x = (_Float16)(O[dt][0] * rl);
        o.y = (_Float16)(O[dt][1] * rl);
        o.z = (_Float16)(O[dt][2] * rl);
        o.w = (_Float16)(O[dt][3] * rl);
        *(f16x4*)(op + dt * 16 + quad * 4) = o;
        O[dt] = (f32x4){0.f, 0.f, 0.f, 0.f};
      }
      m_i = -3e38f; l_i = 0.f;
      // switch Q fragment to group b
      const char* qp = q8 + pbase + (size_t)qrowB * 64;
      aq0v = *(const long*)(qp + quad * 8);
      aq1v = *(const long*)(qp + 32 + quad * 8);
    }
  };

#pragma unroll 1
  for (int u = 0; u < NT; u += 2) {
    body(u, kc, kn);
    if (u + 1 < NT) body(u + 1, kn, kc);
  }

  if (role) {   // tail ships partial state
#pragma unroll
    for (int dt = 0; dt < 4; ++dt)
      *(f32x4*)&Osh[pi][mcol][dt * 16 + quad * 4] = O[dt];
    if (quad == 0) { Msh[pi][mcol] = m_i; Lsh[pi][mcol] = l_i; }
  }
  __syncthreads();
  if (!role) {  // lead merges and stores group b
    float m1 = Msh[pi][mcol], l1 = Lsh[pi][mcol];
    float m = fmaxf(m_i, m1);
    float a0 = exp2f(m_i - m), a1 = exp2f(m1 - m);
    float rl = 1.f / (a0 * l_i + a1 * l1);
    _Float16* op = attn + ((size_t)b * 2048 + qrowB) * 1024 + h * 64;
#pragma unroll
    for (int dt = 0; dt < 4; ++dt) {
      f32x4 o1 = *(const f32x4*)&Osh[pi][mcol][dt * 16 + quad * 4];
      f16x4 o;
      o.x = (_Float16)((a0 * O[dt][0] + a1 * o1[0]) * rl);
      o.y = (_Float16)((a0 * O[dt][1] + a1 * o1[1]) * rl);
      o.z = (_Float16)((a0 * O[dt][2] + a1 * o1[2]) * rl);
      o.w = (_Float16)((a0 * O[dt][3] + a1 * o1[3]) * rl);
      *(f16x4*)(op + dt * 16 + quad * 4) = o;
    }
  }
}

// ---------------- GEMM2: out = attn @ w_proj + b (async staging) ---------
__global__ __launch_bounds__(256) void k_gemm_out(const _Float16* __restrict__ A,
                                                  const _Float16* __restrict__ BT,
                                                  const float* __restrict__ bias,
                                                  float* __restrict__ out) {
  __shared__ __align__(16) _Float16 As[128 * 32];
  __shared__ __align__(16) _Float16 Bs[128 * 32];
  const int tid = threadIdx.x, lane = tid & 63, wave = tid >> 6;
  const int wm = wave >> 1, wn = wave & 1;
  const int mcol = lane & 15, quad = lane >> 4;
  const int m0 = blockIdx.x * 128, n0 = blockIdx.y * 128;
  f32x4 acc[4][4] = {};
  for (int k0 = 0; k0 < 1024; k0 += 32) {
#pragma unroll
    for (int r = 0; r < 2; ++r) {
      int c = tid + r * 256;
      int row = c >> 2, kc = c & 3;
      GLOAD_LDS(A  + (size_t)(m0 + row) * 1024 + k0 + kc * 8, &As[c * 8]);
      GLOAD_LDS(BT + (size_t)(n0 + row) * 1024 + k0 + kc * 8, &Bs[c * 8]);
    }
    __syncthreads();
    f16x8 af[4], bf[4];
#pragma unroll
    for (int tm = 0; tm < 4; ++tm)
      af[tm] = *(const f16x8*)&As[(wm * 64 + tm * 16 + mcol) * 32 + quad * 8];
#pragma unroll
    for (int tn = 0; tn < 4; ++tn)
      bf[tn] = *(const f16x8*)&Bs[(wn * 64 + tn * 16 + mcol) * 32 + quad * 8];
#pragma unroll
    for (int tm = 0; tm < 4; ++tm)
#pragma unroll
      for (int tn = 0; tn < 4; ++tn)
        acc[tm][tn] = __builtin_amdgcn_mfma_f32_16x16x32_f16(af[tm], bf[tn], acc[tm][tn], 0, 0, 0);
    __syncthreads();
  }
#pragma unroll
  for (int tm = 0; tm < 4; ++tm)
#pragma unroll
    for (int tn = 0; tn < 4; ++tn)
#pragma unroll
      for (int reg = 0; reg < 4; ++reg) {
        int row = m0 + wm * 64 + tm * 16 + quad * 4 + reg;
        int col = n0 + wn * 64 + tn * 16 + mcol;
        out[(size_t)row * 1024 + col] = acc[tm][tn][reg] + bias[col];
      }
}

extern "C" void kernel_launch(void* const* d_in, const int* in_sizes, int n_in,
                              void* d_out, int out_size, void* d_ws, size_t ws_size,
                              hipStream_t stream) {
  const float* x      = (const float*)d_in[0];
  const float* w_qkv  = (const float*)d_in[1];
  const float* w_proj = (const float*)d_in[2];
  const float* b_proj = (const float*)d_in[3];
  float* out = (float*)d_out;

  char* ws = (char*)d_ws;
  _Float16* xh   = (_Float16*)ws; ws += (size_t)M1 * C_ * 2;
  _Float16* whT  = (_Float16*)ws; ws += (size_t)3 * C_ * C_ * 2;
  _Float16* wpT  = (_Float16*)ws; ws += (size_t)C_ * C_ * 2;
  _Float16* qh   = (_Float16*)ws; ws += (size_t)BH_ * NDH * 2;
  _Float16* kh   = (_Float16*)ws; ws += (size_t)BH_ * NDH * 2;
  _Float16* vh   = (_Float16*)ws; ws += (size_t)BH_ * NDH * 2;
  char*     q8   = (char*)ws;     ws += (size_t)BH_ * NDH;
  char*     k8   = (char*)ws;     ws += (size_t)BH_ * NDH;
  _Float16* attn = (_Float16*)ws; ws += (size_t)M1 * C_ * 2;
  float*    amx  = (float*)ws;    ws += 256;

  k_cvt16<<<(M1 * C_ / 4 + 255) / 256, 256, 0, stream>>>(x, xh, M1 * C_ / 4);
  k_transmerge<<<1024, 256, 0, stream>>>(w_qkv, w_proj, whT, wpT, (unsigned*)amx);
  k_gemm_qkv<<<dim3(M1 / 128, 3 * C_ / 128), 256, 0, stream>>>(xh, whT, qh, kh, vh, (unsigned*)amx);
  k_quant<<<4096, 256, 0, stream>>>(qh, kh, amx, q8, k8);
  k_flash<<<dim3(32, 32), 256, 0, stream>>>(q8, k8, vh, amx, attn);
  k_gemm_out<<<dim3(M1 / 128, C_ / 128), 256, 0, stream>>>(attn, wpT, b_proj, out);
}